// Round 6
// baseline (1150.255 us; speedup 1.0000x reference)
//
#include <hip/hip_runtime.h>
#include <hip/hip_cooperative_groups.h>

namespace cg = cooperative_groups;

#define DEV __device__ __forceinline__

typedef __attribute__((ext_vector_type(8))) short short8;
typedef __attribute__((ext_vector_type(4))) float floatx4;

constexpr int Tn  = 4096;   // tokens (B*S)
constexpr int Dm  = 2048;   // model dim
constexpr int In  = 1408;   // expert inter dim
constexpr int En  = 8;      // experts
constexpr int SIn = 2816;   // shared inter dim (2*1408)
constexpr int CAP = 10240;  // 8192 pairs + 8*256 padding (segments padded to 256)

constexpr int SH_H = (Tn / 256) * (SIn / 128);    // 352 shared h tiles
constexpr int SH_O = (Tn / 256) * (Dm / 256);     // 128 shared o tiles
constexpr int NBLK = 256;                         // persistent blocks = CUs
constexpr int GSTR = NBLK * 512;                  // grid-stride (threads)
constexpr int TTILES = (Dm / 64) * (In / 64) * En * 3;  // 16896 transpose tiles

DEV unsigned short f2bf(float f) {          // fp32 -> bf16 RNE
  unsigned int u = __float_as_uint(f);
  u += 0x7FFF + ((u >> 16) & 1);
  return (unsigned short)(u >> 16);
}

DEV float bf2f(unsigned short u) {
  return __uint_as_float(((unsigned int)u) << 16);
}

DEV void stg(const char* g, char* l) {
  // async global->LDS, 16B/lane; LDS dst = wave-uniform base + lane*16
  __builtin_amdgcn_global_load_lds(
      (const __attribute__((address_space(1))) unsigned int*)g,
      (__attribute__((address_space(3))) unsigned int*)l, 16, 0, 0);
}

DEV unsigned ldsoff(const void* p) {        // generic LDS ptr -> 32-bit LDS byte offset
  return (unsigned)(unsigned long long)(__attribute__((address_space(3))) const char*)p;
}

#define BARR()  __builtin_amdgcn_s_barrier()
#define LGKM0() do { asm volatile("s_waitcnt lgkmcnt(0)" ::: "memory"); \
                     __builtin_amdgcn_sched_barrier(0); } while (0)
#define LGKM8() asm volatile("s_waitcnt lgkmcnt(8)" ::: "memory")
#define VMC(n)  asm volatile("s_waitcnt vmcnt(" #n ")" ::: "memory")
#define PRIO(x) __builtin_amdgcn_s_setprio(x)

// inline-asm ds_read_b128 (immediate offsets; ordering via LGKM/VMC + barriers)
#define DSR(dst, addr, OFFSTR) \
  asm volatile("ds_read_b128 %0, %1 offset:" OFFSTR : "=v"(dst) : "v"(addr))

#define RDA_LO(af, a) do { \
  DSR(af[0][0], a, "0");     DSR(af[0][1], a, "1024"); \
  DSR(af[1][0], a, "2048");  DSR(af[1][1], a, "3072"); \
  DSR(af[2][0], a, "4096");  DSR(af[2][1], a, "5120"); \
  DSR(af[3][0], a, "6144");  DSR(af[3][1], a, "7168"); } while (0)
#define RDA_HI(af, a) do { \
  DSR(af[0][0], a, "8192");  DSR(af[0][1], a, "9216"); \
  DSR(af[1][0], a, "10240"); DSR(af[1][1], a, "11264"); \
  DSR(af[2][0], a, "12288"); DSR(af[2][1], a, "13312"); \
  DSR(af[3][0], a, "14336"); DSR(af[3][1], a, "15360"); } while (0)
#define RDB_LO(bf, a) do { \
  DSR(bf[0][0], a, "0");    DSR(bf[0][1], a, "1024"); \
  DSR(bf[1][0], a, "2048"); DSR(bf[1][1], a, "3072"); } while (0)
#define RDB_HI(bf, a) do { \
  DSR(bf[2][0], a, "4096"); DSR(bf[2][1], a, "5120"); \
  DSR(bf[3][0], a, "6144"); DSR(bf[3][1], a, "7168"); } while (0)

// ---------------- shared device helpers ----------------

DEV void cvt4(const float* __restrict__ src, unsigned short* __restrict__ dst,
              int n4, int gtid) {
#pragma unroll 1
  for (int i = gtid; i < n4; i += GSTR) {
    float4 v = ((const float4*)src)[i];
    union { unsigned short u[4]; unsigned long long ll; } p;
    p.u[0] = f2bf(v.x); p.u[1] = f2bf(v.y); p.u[2] = f2bf(v.z); p.u[3] = f2bf(v.w);
    *(unsigned long long*)(dst + (long)i * 4) = p.ll;
  }
}

// 64x64 transpose+convert tile, 512 threads, LDS scratch
DEV void transpose_tile(const float* __restrict__ s0, unsigned short* __restrict__ d0,
                        int R, int C, int y, int xb, char* LDSC) {
  float (*tile)[65] = (float(*)[65])LDSC;
  int tilesC = C >> 6;
  int tr = (xb / tilesC) << 6, tc = (xb % tilesC) << 6;
  const float* s = s0 + (long)y * R * C;
  unsigned short* d = d0 + (long)y * R * C;
  int tid = threadIdx.x;
  int rr = tid >> 4, c4 = (tid & 15) << 2;   // 32 rows x 16 float4
  __syncthreads();                            // protect LDS reuse across tiles
#pragma unroll
  for (int p = 0; p < 2; p++) {
    float4 v = *(const float4*)&s[(long)(tr + rr + 32 * p) * C + tc + c4];
    tile[rr + 32 * p][c4]     = v.x;
    tile[rr + 32 * p][c4 + 1] = v.y;
    tile[rr + 32 * p][c4 + 2] = v.z;
    tile[rr + 32 * p][c4 + 3] = v.w;
  }
  __syncthreads();
  int oc = tid >> 5, i2 = (tid & 31) << 1;   // 16 out-rows x 32 pairs
#pragma unroll
  for (int p = 0; p < 4; p++) {
    int j = oc + 16 * p;
    union { unsigned short u[2]; unsigned int w; } pk;
    pk.u[0] = f2bf(tile[i2][j]);
    pk.u[1] = f2bf(tile[i2 + 1][j]);
    *(unsigned int*)&d[(long)(tc + j) * R + tr + i2] = pk.w;
  }
}

// ---------------- 8-phase 256-row GEMM core ----------------
// BM=256, BK=64, 512 threads = 8 waves (2M x 4N), per-wave C 128x64.
// LDS (dynamic 128KB): [buf0: A 32K | B 32K][buf1: A 32K | B 32K]
// st_16x32 XOR swizzle via pre-swizzled global source (linear gload_lds dest).

DEV void mm16(floatx4 (&acc)[8][4], const short8 (&af)[4][2],
              const short8 (&bf)[4][2], int mq, int nq) {
#pragma unroll
  for (int i = 0; i < 4; i++)
#pragma unroll
    for (int n = 0; n < 2; n++)
#pragma unroll
      for (int kk = 0; kk < 2; kk++)
        acc[4 * mq + i][2 * nq + n] = __builtin_amdgcn_mfma_f32_16x16x32_bf16(
            af[i][kk], bf[2 * nq + n][kk], acc[4 * mq + i][2 * nq + n], 0, 0, 0);
}

// chunk c (c = j*512 + tid) lands at linear LDS byte c*16; swizzled layout:
// row = (c>>7)*16 + ((c>>2)&15), colb = ((c>>6)&1)*64 + (((c&3)<<4) ^ (c&32 ? 32 : 0))
DEV void chunk_rc(int c, int& rowh, int& colb) {
  rowh = ((c >> 7) << 4) | ((c >> 2) & 15);
  colb = (((c >> 6) & 1) << 6) | ((((c & 3) << 4)) ^ ((c & 32) ? 32 : 0));
}

DEV void gemm_core(char* LDS, const char* (&gA)[2][2], const char* (&gB)[2][2],
                   floatx4 (&acc)[8][4], int NT, int wm, int wn, int wv, int aswz) {
  const int bsel = (wn >> 1) * 16384 + ((wn & 1) << 13);
  const int wb = wv * 1024;
  unsigned base = ldsoff(LDS);
  unsigned aA0 = base + wm * 16384 + aswz;
  unsigned aB0 = base + 32768 + bsel + aswz;
  unsigned aA1 = aA0 + 65536, aB1 = aB0 + 65536;
  // prologue: tile0 complete (8 loads) + tile1 j0 rounds A,B (4 loads)
  stg(gB[0][0], LDS + 32768 + wb);
  stg(gB[1][0], LDS + 32768 + 16384 + wb);
  stg(gB[0][1], LDS + 32768 + 8192 + wb);
  stg(gB[1][1], LDS + 32768 + 16384 + 8192 + wb);
  stg(gA[0][0], LDS + wb);
  stg(gA[1][0], LDS + 16384 + wb);
  stg(gA[0][1], LDS + 8192 + wb);
  stg(gA[1][1], LDS + 16384 + 8192 + wb);
  stg(gA[0][0] + 128, LDS + 65536 + wb);
  stg(gA[1][0] + 128, LDS + 65536 + 16384 + wb);
  stg(gB[0][0] + 128, LDS + 65536 + 32768 + wb);
  stg(gB[1][0] + 128, LDS + 65536 + 32768 + 16384 + wb);
  VMC(4);
  BARR();
  short8 af[4][2], bf[4][2];

  auto tile = [&](int t, int b, unsigned aA, unsigned aB) {
    char* An = LDS + ((b ^ 1) << 16);
    char* Bn = An + 32768;
    char* Ac = LDS + (b << 16);
    char* Bc = Ac + 32768;
    const int kn = (t + 1) << 7, ka = (t + 2) << 7;
    const bool s1 = (t + 1 < NT), s2 = (t + 2 < NT);
    // ---- phase 0: quadrant (mq0,nq0); stage B(t+1) j1
    RDA_LO(af, aA); RDB_LO(bf, aB);
    if (s1) { stg(gB[0][1] + kn, Bn + 8192 + wb);
              stg(gB[1][1] + kn, Bn + 16384 + 8192 + wb); }
    LGKM8(); BARR(); LGKM0(); PRIO(1); mm16(acc, af, bf, 0, 0); PRIO(0); BARR();
    // ---- phase 1: (mq0,nq1); stage A(t+1) j1
    RDB_HI(bf, aB);
    if (s1) { stg(gA[0][1] + kn, An + 8192 + wb);
              stg(gA[1][1] + kn, An + 16384 + 8192 + wb); }
    BARR(); LGKM0(); PRIO(1); mm16(acc, af, bf, 0, 1); PRIO(0); BARR();
    // ---- phase 2: (mq1,nq0); A-j0 of current buf dead -> stage A(t+2) j0
    RDA_HI(af, aA);
    if (s2) { stg(gA[0][0] + ka, Ac + wb);
              stg(gA[1][0] + ka, Ac + 16384 + wb); }
    BARR(); LGKM0(); PRIO(1); mm16(acc, af, bf, 1, 0); PRIO(0); BARR();
    // ---- phase 3: (mq1,nq1); B-j0 of current buf dead -> stage B(t+2) j0
    if (s2) { stg(gB[0][0] + ka, Bc + wb);
              stg(gB[1][0] + ka, Bc + 16384 + wb); }
    BARR(); LGKM0(); PRIO(1); mm16(acc, af, bf, 1, 1); PRIO(0);
    if (s2)      { VMC(4); }   // all of t+1 landed; t+2 j0 stays in flight
    else if (s1) { VMC(0); }   // pipeline drain near the end
    BARR();
  };
#pragma unroll 1
  for (int t2 = 0; t2 < NT; t2 += 2) {
    tile(t2, 0, aA0, aB0);
    tile(t2 + 1, 1, aA1, aB1);
  }
}

// ---------------- stage 1 (h) body ----------------
// B tile interleaves W1/W3 in 32-row chunks; wave wn covers cols
// n0+wn*32..+31: acc[.][0..1]=h1 frags, acc[.][2..3]=h3 frags.

DEV void h_body(const unsigned short* Xb, const unsigned short* B1p,
                const unsigned short* B3p, unsigned short* ap, int Nact,
                int m0, int n0, const int* ptok, bool routed, char* LDS) {
  int tid = threadIdx.x, wv = tid >> 6, lane = tid & 63;
  int wm = wv >> 2, wn = wv & 3;
  int fr = lane & 15, fq = lane >> 4;
  int aswz = fr * 64 + ((fq * 16) ^ ((fr & 8) << 2));

  const char* gA[2][2]; const char* gB[2][2];
#pragma unroll
  for (int j = 0; j < 2; j++) {
    int rowh, colb;
    chunk_rc(j * 512 + tid, rowh, colb);
#pragma unroll
    for (int h = 0; h < 2; h++) {
      int grA = m0 + h * 128 + rowh;
      long ra = routed ? (long)ptok[grA] : (long)grA;
      gA[h][j] = (const char*)Xb + ra * (long)(Dm * 2) + colb;
      int rt = h * 128 + rowh;
      const unsigned short* src = ((rt >> 5) & 1) ? B3p : B1p;
      long rb = (long)n0 + ((rt >> 6) << 5) + (rt & 31);
      gB[h][j] = (const char*)src + rb * (long)(Dm * 2) + colb;
    }
  }
  floatx4 acc[8][4];
#pragma unroll
  for (int i = 0; i < 8; i++)
#pragma unroll
    for (int n = 0; n < 4; n++) acc[i][n] = (floatx4)0.0f;

  gemm_core(LDS, gA, gB, acc, Dm / 64, wm, wn, wv, aswz);

#pragma unroll
  for (int mi = 0; mi < 8; mi++)
#pragma unroll
    for (int n = 0; n < 2; n++)
#pragma unroll
      for (int r = 0; r < 4; r++) {
        int row = m0 + wm * 128 + mi * 16 + fq * 4 + r;
        int col = n0 + wn * 32 + n * 16 + fr;
        float h1 = acc[mi][n][r], h3 = acc[mi][n + 2][r];
        float v = h1 / (1.0f + __expf(-h1)) * h3;
        ap[(long)row * Nact + col] = f2bf(v);
      }
}

DEV void h_phase(const unsigned short* Xb, const unsigned short* W1t,
                 const unsigned short* W3t, const unsigned short* sw1b,
                 const unsigned short* sw3b, unsigned short* act,
                 unsigned short* actS, const int* ptok, const int* offs,
                 char* LDS) {
  const int Mr = offs[En] >> 8;             // live routed m-tiles
  const int RT = Mr * (In / 128);           // live routed tiles (no empties)
  const int TT = RT + SH_H;
  // XCD-chunked assignment: 32 same-XCD blocks walk a contiguous tile range
  const int per = (TT + 7) >> 3;
  const int xcd = blockIdx.x & 7, lix = blockIdx.x >> 3;
#pragma unroll 1
  for (int i = lix; i < per; i += 32) {
    int t = xcd * per + i;
    if (t >= TT) break;
    if (t < RT) {
      int m0 = (t % Mr) * 256, n0 = (t / Mr) * 128;
      int e = 0;
      while (!(m0 >= offs[e] && m0 < offs[e + 1])) e++;
      h_body(Xb, W1t + (long)e * In * Dm, W3t + (long)e * In * Dm,
             act, In, m0, n0, ptok, true, LDS);
    } else {
      int u = t - RT;
      int m0 = (u & 15) * 256, n0 = (u >> 4) * 128;
      h_body(Xb, sw1b, sw3b, actS, SIn, m0, n0, nullptr, false, LDS);
    }
  }
}

// ---------------- stage 2 (o) body ----------------

DEV void o_core(const unsigned short* Apt, const unsigned short* Bpt,
                int lda, int ldb, int NT, int m0, int n0,
                floatx4 (&acc)[8][4], char* LDS) {
  int tid = threadIdx.x, wv = tid >> 6, lane = tid & 63;
  int wm = wv >> 2, wn = wv & 3;
  int fr = lane & 15, fq = lane >> 4;
  int aswz = fr * 64 + ((fq * 16) ^ ((fr & 8) << 2));

  const char* gA[2][2]; const char* gB[2][2];
#pragma unroll
  for (int j = 0; j < 2; j++) {
    int rowh, colb;
    chunk_rc(j * 512 + tid, rowh, colb);
#pragma unroll
    for (int h = 0; h < 2; h++) {
      gA[h][j] = (const char*)Apt + (long)(m0 + h * 128 + rowh) * (lda * 2) + colb;
      gB[h][j] = (const char*)Bpt + (long)(n0 + h * 128 + rowh) * (ldb * 2) + colb;
    }
  }
#pragma unroll
  for (int i = 0; i < 8; i++)
#pragma unroll
    for (int n = 0; n < 4; n++) acc[i][n] = (floatx4)0.0f;

  gemm_core(LDS, gA, gB, acc, NT, wm, wn, wv, aswz);
}

DEV void o_phase(const unsigned short* act, const unsigned short* actS,
                 const unsigned short* W2t, const unsigned short* sw2b,
                 unsigned short* yR, float* out, const int* offs, char* LDS) {
  const int Mr = offs[En] >> 8;
  const int RT = Mr * (Dm / 256);           // live routed o tiles
  const int TT = SH_O + RT;                 // shared tiles FIRST
  int lane = threadIdx.x & 63, wv = threadIdx.x >> 6;
  int wm = wv >> 2, wn = wv & 3;
  int fr = lane & 15, fq = lane >> 4;
  const int per = (TT + 7) >> 3;
  const int xcd = blockIdx.x & 7, lix = blockIdx.x >> 3;
#pragma unroll 1
  for (int i = lix; i < per; i += 32) {
    int t = xcd * per + i;
    if (t >= TT) break;
    floatx4 acc[8][4];
    if (t >= SH_O) {
      int u = t - SH_O;
      int m0 = (u % Mr) * 256, n0 = (u / Mr) * 256;
      int e = 0;
      while (!(m0 >= offs[e] && m0 < offs[e + 1])) e++;
      o_core(act, W2t + (long)e * Dm * In, In, In, In / 64, m0, n0, acc, LDS);
#pragma unroll
      for (int mi = 0; mi < 8; mi++)
#pragma unroll
        for (int r = 0; r < 4; r++) {
          int row = m0 + wm * 128 + mi * 16 + fq * 4 + r;
#pragma unroll
          for (int ni = 0; ni < 4; ni++) {
            int col = n0 + wn * 64 + ni * 16 + fr;
            yR[(long)row * Dm + col] = f2bf(acc[mi][ni][r]);
          }
        }
    } else {
      int u = t;
      int m0 = (u & 15) * 256, n0 = (u >> 4) * 256;
      o_core(actS, sw2b, SIn, SIn, SIn / 64, m0, n0, acc, LDS);
#pragma unroll
      for (int mi = 0; mi < 8; mi++)
#pragma unroll
        for (int r = 0; r < 4; r++) {
          int row = m0 + wm * 128 + mi * 16 + fq * 4 + r;
#pragma unroll
          for (int ni = 0; ni < 4; ni++) {
            int col = n0 + wn * 64 + ni * 16 + fr;
            out[(long)row * Dm + col] = acc[mi][ni][r];
          }
        }
    }
  }
}

// ---------------- router body (fp64 to match numpy top-k) ----------------

DEV void router_body(const float* x, const float* gw, const float* bias,
                     int* route_e, float* route_w) {
  int wv = threadIdx.x >> 6, lane = threadIdx.x & 63;
#pragma unroll 1
  for (int t = blockIdx.x * 8 + wv; t < Tn; t += NBLK * 8) {
    const float* xr = x + (long)t * Dm;
    double acc[En];
#pragma unroll
    for (int e = 0; e < En; e++) acc[e] = 0.0;
    for (int d = lane; d < Dm; d += 64) {
      double xv = (double)xr[d];
#pragma unroll
      for (int e = 0; e < En; e++) acc[e] += xv * (double)gw[e * Dm + d];
    }
#pragma unroll
    for (int off = 32; off > 0; off >>= 1) {
#pragma unroll
      for (int e = 0; e < En; e++) acc[e] += __shfl_down(acc[e], off);
    }
    if (lane == 0) {
      double sc[En], sel[En];
#pragma unroll
      for (int e = 0; e < En; e++) {
        sc[e] = 1.0 / (1.0 + exp(-acc[e]));
        sel[e] = sc[e] + (double)bias[e];
      }
      int i0 = 0;
#pragma unroll
      for (int e = 1; e < En; e++) if (sel[e] > sel[i0]) i0 = e;
      int i1 = (i0 == 0) ? 1 : 0;
#pragma unroll
      for (int e = 0; e < En; e++) if (e != i0 && sel[e] > sel[i1]) i1 = e;
      double s = sc[i0] + sc[i1];
      if (s < 1e-12) s = 1e-12;
      route_e[t * 2] = i0;  route_e[t * 2 + 1] = i1;
      route_w[t * 2] = (float)(sc[i0] / s);  route_w[t * 2 + 1] = (float)(sc[i1] / s);
    }
  }
}

// ---------------- cooperative mega-kernel: all 5 phases, 1 dispatch ----------------

__global__ __launch_bounds__(512, 1)
void moe_mega(const float* __restrict__ x, const float* __restrict__ gw,
              const float* __restrict__ bias,
              const float* __restrict__ sw1, const float* __restrict__ sw3,
              const float* __restrict__ sw2,
              const float* __restrict__ W1, const float* __restrict__ W3,
              const float* __restrict__ W2,
              unsigned short* __restrict__ Xb,
              unsigned short* __restrict__ sw1b, unsigned short* __restrict__ sw3b,
              unsigned short* __restrict__ sw2b,
              unsigned short* __restrict__ W1t, unsigned short* __restrict__ W3t,
              unsigned short* __restrict__ W2t,
              unsigned short* __restrict__ act, unsigned short* __restrict__ actS,
              unsigned short* __restrict__ yR,
              int* __restrict__ route_e, float* __restrict__ route_w,
              int* __restrict__ offs, int* __restrict__ ptok,
              int* __restrict__ pslot, float* __restrict__ out) {
  extern __shared__ char LDS[];
  cg::grid_group grid = cg::this_grid();
  int gtid = blockIdx.x * 512 + threadIdx.x;

  // ===== phase A: router + ptok init + converts + transposes =====
  router_body(x, gw, bias, route_e, route_w);
  if (gtid < CAP) ptok[gtid] = 0;           // pad slots gather token 0
  cvt4(x,   Xb,   Tn * Dm / 4, gtid);
  cvt4(sw1, sw1b, SIn * Dm / 4, gtid);
  cvt4(sw3, sw3b, SIn * Dm / 4, gtid);
  cvt4(sw2, sw2b, Dm * SIn / 4, gtid);
  {
    const int TBZ = (Dm / 64) * (In / 64);  // 704 tiles per (z,y)
#pragma unroll 1
    for (int tb = blockIdx.x; tb < TTILES; tb += NBLK) {
      int z = tb / (TBZ * En);
      int rem = tb % (TBZ * En);
      int y = rem / TBZ, xb = rem % TBZ;
      if (z == 0)      transpose_tile(W1, W1t, Dm, In, y, xb, LDS);
      else if (z == 1) transpose_tile(W3, W3t, Dm, In, y, xb, LDS);
      else             transpose_tile(W2, W2t, In, Dm, y, xb, LDS);
    }
  }
  __threadfence();
  grid.sync();

  // ===== phase B: offsets + scatter (block 0) =====
  if (blockIdx.x == 0) {
    int* lcnt  = (int*)LDS;
    int* lfill = lcnt + En;
    int tid = threadIdx.x;
    if (tid < En) lcnt[tid] = 0;
    __syncthreads();
    for (int i = tid; i < Tn * 2; i += 512) atomicAdd(&lcnt[route_e[i]], 1);
    __syncthreads();
    if (tid == 0) {
      int off = 0;
      for (int e = 0; e < En; e++) {
        offs[e] = off; lfill[e] = off;
        off += (lcnt[e] + 255) & ~255;      // pad each expert segment to 256
      }
      offs[En] = off;
    }
    __syncthreads();
    for (int i = tid; i < Tn * 2; i += 512) {
      int slot = atomicAdd(&lfill[route_e[i]], 1);
      ptok[slot] = i >> 1;
      pslot[i] = slot;
    }
  }
  __threadfence();
  grid.sync();

  // ===== phase C: h GEMM =====
  h_phase(Xb, W1t, W3t, sw1b, sw3b, act, actS, ptok, offs, LDS);
  __threadfence();
  grid.sync();

  // ===== phase D: o GEMM =====
  o_phase(act, actS, W2t, sw2b, yR, out, offs, LDS);
  __threadfence();
  grid.sync();

  // ===== phase E: combine out[t] += w0*yR[s0] + w1*yR[s1] =====
#pragma unroll 1
  for (int idx = gtid; idx < Tn * (Dm / 4); idx += GSTR) {
    int t = idx >> 9, c4 = idx & 511;       // Dm/4 = 512
    int s0 = pslot[t * 2], s1 = pslot[t * 2 + 1];
    float w0 = route_w[t * 2], w1 = route_w[t * 2 + 1];
    ushort4 a = ((const ushort4*)(yR + (long)s0 * Dm))[c4];
    ushort4 b = ((const ushort4*)(yR + (long)s1 * Dm))[c4];
    float4* op = (float4*)(out + (long)t * Dm) + c4;
    float4 o = *op;
    o.x += w0 * bf2f(a.x) + w1 * bf2f(b.x);
    o.y += w0 * bf2f(a.y) + w1 * bf2f(b.y);
    o.z += w0 * bf2f(a.z) + w1 * bf2f(b.z);
    o.w += w0 * bf2f(a.w) + w1 * bf2f(b.w);
    *op = o;
  }
}

// ---------------- fallback kernels (r5 path, used if coop launch fails) ----------------

__global__ void fb_prep(const float* __restrict__ x, const float* __restrict__ gw,
                        const float* __restrict__ bias,
                        const float* __restrict__ sw1, const float* __restrict__ sw3,
                        const float* __restrict__ sw2,
                        const float* __restrict__ W1, const float* __restrict__ W3,
                        const float* __restrict__ W2,
                        unsigned short* __restrict__ Xb,
                        unsigned short* __restrict__ sw1b, unsigned short* __restrict__ sw3b,
                        unsigned short* __restrict__ sw2b,
                        unsigned short* __restrict__ W1t, unsigned short* __restrict__ W3t,
                        unsigned short* __restrict__ W2t,
                        int* __restrict__ route_e, float* __restrict__ route_w,
                        int* __restrict__ ptok) {
  __shared__ char SL[64 * 65 * 4];
  int gtid = blockIdx.x * 512 + threadIdx.x;
  router_body(x, gw, bias, route_e, route_w);
  if (gtid < CAP) ptok[gtid] = 0;
  cvt4(x,   Xb,   Tn * Dm / 4, gtid);
  cvt4(sw1, sw1b, SIn * Dm / 4, gtid);
  cvt4(sw3, sw3b, SIn * Dm / 4, gtid);
  cvt4(sw2, sw2b, Dm * SIn / 4, gtid);
  const int TBZ = (Dm / 64) * (In / 64);
#pragma unroll 1
  for (int tb = blockIdx.x; tb < TTILES; tb += NBLK) {
    int z = tb / (TBZ * En);
    int rem = tb % (TBZ * En);
    int y = rem / TBZ, xb = rem % TBZ;
    if (z == 0)      transpose_tile(W1, W1t, Dm, In, y, xb, SL);
    else if (z == 1) transpose_tile(W3, W3t, Dm, In, y, xb, SL);
    else             transpose_tile(W2, W2t, In, Dm, y, xb, SL);
  }
}

__global__ void fb_offscatter(const int* __restrict__ re, int* __restrict__ offs,
                              int* __restrict__ ptok, int* __restrict__ pslot) {
  __shared__ int lcnt[En], lfill[En];
  int tid = threadIdx.x;
  if (tid < En) lcnt[tid] = 0;
  __syncthreads();
  for (int i = tid; i < Tn * 2; i += 1024) atomicAdd(&lcnt[re[i]], 1);
  __syncthreads();
  if (tid == 0) {
    int off = 0;
    for (int e = 0; e < En; e++) {
      offs[e] = off; lfill[e] = off;
      off += (lcnt[e] + 255) & ~255;
    }
    offs[En] = off;
  }
  __syncthreads();
  for (int i = tid; i < Tn * 2; i += 1024) {
    int slot = atomicAdd(&lfill[re[i]], 1);
    ptok[slot] = i >> 1;
    pslot[i] = slot;
  }
}

__global__ __launch_bounds__(512, 1)
void fb_h(const unsigned short* __restrict__ Xb, const unsigned short* __restrict__ W1t,
          const unsigned short* __restrict__ W3t, const unsigned short* __restrict__ sw1b,
          const unsigned short* __restrict__ sw3b, unsigned short* __restrict__ act,
          unsigned short* __restrict__ actS, const int* __restrict__ ptok,
          const int* __restrict__ offs) {
  extern __shared__ char LDS[];
  h_phase(Xb, W1t, W3t, sw1b, sw3b, act, actS, ptok, offs, LDS);
}

__global__ __launch_bounds__(512, 1)
void fb_o(const unsigned short* __restrict__ act, const unsigned short* __restrict__ actS,
          const unsigned short* __restrict__ W2t, const unsigned short* __restrict__ sw2b,
          unsigned short* __restrict__ yR, float* __restrict__ out,
          const int* __restrict__ offs) {
  extern __shared__ char LDS[];
  o_phase(act, actS, W2t, sw2b, yR, out, offs, LDS);
}

__global__ void fb_combine(const unsigned short* __restrict__ yR,
                           const int* __restrict__ pslot,
                           const float* __restrict__ rw,
                           float* __restrict__ out) {
  int idx = blockIdx.x * 256 + threadIdx.x;
  int t = idx >> 9, c4 = idx & 511;
  int s0 = pslot[t * 2], s1 = pslot[t * 2 + 1];
  float w0 = rw[t * 2], w1 = rw[t * 2 + 1];
  ushort4 a = ((const ushort4*)(yR + (long)s0 * Dm))[c4];
  ushort4 b = ((const ushort4*)(yR + (long)s1 * Dm))[c4];
  float4* op = (float4*)(out + (long)t * Dm) + c4;
  float4 o = *op;
  o.x += w0 * bf2f(a.x) + w1 * bf2f(b.x);
  o.y += w0 * bf2f(a.y) + w1 * bf2f(b.y);
  o.z += w0 * bf2f(a.z) + w1 * bf2f(b.z);
  o.w += w0 * bf2f(a.w) + w1 * bf2f(b.w);
  *op = o;
}

// ---------------- launch ----------------

extern "C" void kernel_launch(void* const* d_in, const int* in_sizes, int n_in,
                              void* d_out, int out_size, void* d_ws, size_t ws_size,
                              hipStream_t stream) {
  const float* x    = (const float*)d_in[0];
  const float* gw   = (const float*)d_in[1];
  const float* bias = (const float*)d_in[2];
  const float* W1   = (const float*)d_in[3];
  const float* W3   = (const float*)d_in[4];
  const float* W2   = (const float*)d_in[5];
  const float* sw1  = (const float*)d_in[6];
  const float* sw3  = (const float*)d_in[7];
  const float* sw2  = (const float*)d_in[8];
  float* out = (float*)d_out;

  static bool attr_done = false;
  if (!attr_done) {
    hipFuncSetAttribute(reinterpret_cast<const void*>(moe_mega),
                        hipFuncAttributeMaxDynamicSharedMemorySize, 131072);
    hipFuncSetAttribute(reinterpret_cast<const void*>(fb_h),
                        hipFuncAttributeMaxDynamicSharedMemorySize, 131072);
    hipFuncSetAttribute(reinterpret_cast<const void*>(fb_o),
                        hipFuncAttributeMaxDynamicSharedMemorySize, 131072);
    attr_done = true;
  }

  char* p = (char*)d_ws;
  auto alloc = [&](size_t bytes) {
    char* r = p; p += (bytes + 255) & ~(size_t)255; return r;
  };
  unsigned short* Xb   = (unsigned short*)alloc((size_t)Tn * Dm * 2);
  unsigned short* W1t  = (unsigned short*)alloc((size_t)En * In * Dm * 2);
  unsigned short* W3t  = (unsigned short*)alloc((size_t)En * In * Dm * 2);
  unsigned short* W2t  = (unsigned short*)alloc((size_t)En * Dm * In * 2);
  unsigned short* sw1b = (unsigned short*)alloc((size_t)SIn * Dm * 2);
  unsigned short* sw3b = (unsigned short*)alloc((size_t)SIn * Dm * 2);
  unsigned short* sw2b = (unsigned short*)alloc((size_t)Dm * SIn * 2);
  unsigned short* act  = (unsigned short*)alloc((size_t)CAP * In * 2);
  unsigned short* actS = (unsigned short*)alloc((size_t)Tn * SIn * 2);
  unsigned short* yR   = (unsigned short*)alloc((size_t)CAP * Dm * 2);
  int*   route_e = (int*)alloc(Tn * 2 * 4);
  float* route_w = (float*)alloc(Tn * 2 * 4);
  int*   offs    = (int*)alloc(256);
  int*   ptok    = (int*)alloc(CAP * 4);
  int*   pslot   = (int*)alloc(Tn * 2 * 4);

  void* args[] = {
    (void*)&x, (void*)&gw, (void*)&bias, (void*)&sw1, (void*)&sw3, (void*)&sw2,
    (void*)&W1, (void*)&W3, (void*)&W2,
    (void*)&Xb, (void*)&sw1b, (void*)&sw3b, (void*)&sw2b,
    (void*)&W1t, (void*)&W3t, (void*)&W2t,
    (void*)&act, (void*)&actS, (void*)&yR,
    (void*)&route_e, (void*)&route_w, (void*)&offs, (void*)&ptok, (void*)&pslot,
    (void*)&out
  };
  hipError_t err = hipLaunchCooperativeKernel(
      reinterpret_cast<const void*>(moe_mega), dim3(NBLK), dim3(512),
      args, 131072, stream);

  if (err != hipSuccess) {
    // fallback: proven 5-dispatch path
    fb_prep<<<NBLK, 512, 0, stream>>>(x, gw, bias, sw1, sw3, sw2, W1, W3, W2,
                                      Xb, sw1b, sw3b, sw2b, W1t, W3t, W2t,
                                      route_e, route_w, ptok);
    fb_offscatter<<<1, 1024, 0, stream>>>(route_e, offs, ptok, pslot);
    fb_h<<<NBLK, 512, 131072, stream>>>(Xb, W1t, W3t, sw1b, sw3b, act, actS, ptok, offs);
    fb_o<<<NBLK, 512, 131072, stream>>>(act, actS, W2t, sw2b, yR, out, offs);
    fb_combine<<<Tn * (Dm / 4) / 256, 256, 0, stream>>>(yR, pslot, route_w, out);
  }
}